// Round 4
// baseline (951.376 us; speedup 1.0000x reference)
//
#include <hip/hip_runtime.h>
#include <hip/hip_bf16.h>
#include <math.h>

#define E_DIM    64
#define N_EMBED  1024
#define N_TOKENS 262144
#define QCAP     65536

typedef __attribute__((ext_vector_type(8)))  short bf16x8;
typedef __attribute__((ext_vector_type(16))) float f32x16;

// ---------------------------------------------------------------------------
// Reference semantics (verified absmax 0.0 in rounds 2 & 3): f32 numpy mirror
//   b_j: single fmaf chain ascending k;  a: AVX512 pairwise;  c_j: sequential
//   dist = fl(fl(a - 2b) + c); argmin first-min-wins.
// Round 4: screen computes s_hat = 3 + c - 2*b~ entirely inside MFMA
// (3-pass bf16 split of -2e, plus one c-fold pass), tracks the top-2 via
// monotone u32 bit-keys (2-5 VALU ops/element), certifies the winner with a
// rigorous error bound, and queues uncertified tokens (~2-3%) to an exact
// reference-replica fallback. 64 tokens/wave amortizes LDS reads.
// ---------------------------------------------------------------------------

__device__ __forceinline__ short f2bf_bits(float f) {
    __hip_bfloat16 h = __float2bfloat16(f);
    return *reinterpret_cast<short*>(&h);
}
__device__ __forceinline__ float bfbits2f(short s) {
    unsigned int u = ((unsigned int)(unsigned short)s) << 16;
    return __uint_as_float(u);
}

// c_j = sequential sum of e^2 (reference replica) + bf16(c) for the MFMA fold.
__global__ __launch_bounds__(256) void vq_csum_kernel(const float* __restrict__ emb,
                                                      float* __restrict__ c_out,
                                                      unsigned short* __restrict__ cbf) {
#pragma clang fp contract(off)
    const int j = blockIdx.x * 256 + threadIdx.x;
    if (j >= N_EMBED) return;
    float e = emb[j];
    float s = e * e;
    for (int k = 1; k < E_DIM; ++k) {
        float ek = emb[k * N_EMBED + j];
        float pk = ek * ek;
        s = s + pk;
    }
    c_out[j] = s;
    cbf[j] = (unsigned short)f2bf_bits(s);
}

// split -2*e into bf16 hi/lo, transposed to [code][k]; also emit embed copy.
__global__ __launch_bounds__(256) void vq_prep_split(const float* __restrict__ emb,
                                                     short* __restrict__ ehiT,
                                                     short* __restrict__ eloT,
                                                     float* __restrict__ out_e) {
    const int t = blockIdx.x * 256 + threadIdx.x;   // 0..65535
    const int k = t >> 10, n = t & 1023;
    float e = emb[t];
    float m2 = -2.0f * e;
    short hb = f2bf_bits(m2);
    float hf = bfbits2f(hb);
    short lb = f2bf_bits(m2 - hf);
    ehiT[n * E_DIM + k] = hb;
    eloT[n * E_DIM + k] = lb;
    out_e[t] = e;
}

__global__ __launch_bounds__(256, 2) void vq_screen_kernel(
    const float* __restrict__ in,
    const short* __restrict__ ehiT, const short* __restrict__ eloT,
    const unsigned short* __restrict__ cbf,
    float* __restrict__ out_idx,
    unsigned int* __restrict__ qcnt, unsigned int* __restrict__ queue)
{
    // slot-major LDS: [8 k-slots][128 codes] x 16B -> contiguous b128 r/w
    __shared__ uint4 lds_hi[8 * 128];
    __shared__ uint4 lds_lo[8 * 128];
    __shared__ unsigned short lds_cb[128];

    const int t = threadIdx.x;
    const int wave = t >> 6, l = t & 63, col = l & 31, h = l >> 5;
    const int base = blockIdx.x * 256 + wave * 64;
    const int tok0 = base + col, tok1 = base + 32 + col;

    // ---- B operands for two token groups; sax/a partials (this k-half)
    bf16x8 bhi0[4], blo0[4], bhi1[4], blo1[4];
    float sax0h = 0.f, sax1h = 0.f, a0h = 0.f, a1h = 0.f;
    {
        const float* xr = in + (size_t)tok0 * E_DIM;
#pragma unroll
        for (int s = 0; s < 4; ++s) {
            float4 u0 = *reinterpret_cast<const float4*>(xr + s * 16 + h * 8);
            float4 u1 = *reinterpret_cast<const float4*>(xr + s * 16 + h * 8 + 4);
            float xs[8] = {u0.x, u0.y, u0.z, u0.w, u1.x, u1.y, u1.z, u1.w};
#pragma unroll
            for (int j = 0; j < 8; ++j) {
                float x = xs[j];
                sax0h += fabsf(x);
                a0h = fmaf(x, x, a0h);
                short hb = f2bf_bits(x);
                bhi0[s][j] = hb;
                blo0[s][j] = f2bf_bits(x - bfbits2f(hb));
            }
        }
    }
    {
        const float* xr = in + (size_t)tok1 * E_DIM;
#pragma unroll
        for (int s = 0; s < 4; ++s) {
            float4 u0 = *reinterpret_cast<const float4*>(xr + s * 16 + h * 8);
            float4 u1 = *reinterpret_cast<const float4*>(xr + s * 16 + h * 8 + 4);
            float xs[8] = {u0.x, u0.y, u0.z, u0.w, u1.x, u1.y, u1.z, u1.w};
#pragma unroll
            for (int j = 0; j < 8; ++j) {
                float x = xs[j];
                sax1h += fabsf(x);
                a1h = fmaf(x, x, a1h);
                short hb = f2bf_bits(x);
                bhi1[s][j] = hb;
                blo1[s][j] = f2bf_bits(x - bfbits2f(hb));
            }
        }
    }

    // ones frag for the c-fold pass: k-slots 0,1 = 1.0 (h=0 lanes only)
    bf16x8 ones;
#pragma unroll
    for (int j = 0; j < 8; ++j) ones[j] = 0;
    if (h == 0) { ones[0] = (short)0x3F80; ones[1] = (short)0x3F80; }

    // global trackers: (value-bits m, code) for best; value-bits for 2nd
    unsigned int g1m0 = 0xFFFFFFFFu, g1c0 = 1023u, g2m0 = 0xFFFFFFFFu;
    unsigned int g1m1 = 0xFFFFFFFFu, g1c1 = 1023u, g2m1 = 0xFFFFFFFFu;

    for (int cb = 0; cb < N_EMBED; cb += 128) {
        __syncthreads();
        {   // stage 128 codes: threads 0-127 hi rows, 128-255 lo rows
            const int code = t & 127;
            const short* src = ((t < 128) ? ehiT : eloT) + (size_t)(cb + code) * E_DIM;
            uint4* dst = (t < 128) ? lds_hi : lds_lo;
            const uint4* s4 = reinterpret_cast<const uint4*>(src);
#pragma unroll
            for (int j = 0; j < 8; ++j) dst[j * 128 + code] = s4[j];
            if (t < 128) lds_cb[code] = cbf[cb + code];
        }
        __syncthreads();

        // per-chunk key trackers per token group
        unsigned int k10 = 0xFFFFFFFFu, k20 = 0xFFFFFFFFu;
        unsigned int k11 = 0xFFFFFFFFu, k21 = 0xFFFFFFFFu;

#pragma unroll
        for (int tp = 0; tp < 2; ++tp) {
            const int c0 = tp * 64 + col;
            f32x16 aA0, aA1, aB0, aB1;
#pragma unroll
            for (int r = 0; r < 16; ++r) { aA0[r] = 0.f; aA1[r] = 0.f; aB0[r] = 0.f; aB1[r] = 0.f; }
#pragma unroll
            for (int s = 0; s < 4; ++s) {
                const int slot = 2 * s + h;
                bf16x8 ahA = *reinterpret_cast<const bf16x8*>(&lds_hi[slot * 128 + c0]);
                bf16x8 alA = *reinterpret_cast<const bf16x8*>(&lds_lo[slot * 128 + c0]);
                bf16x8 ahB = *reinterpret_cast<const bf16x8*>(&lds_hi[slot * 128 + c0 + 32]);
                bf16x8 alB = *reinterpret_cast<const bf16x8*>(&lds_lo[slot * 128 + c0 + 32]);
                aA0 = __builtin_amdgcn_mfma_f32_32x32x16_bf16(ahA, bhi0[s], aA0, 0, 0, 0);
                aA0 = __builtin_amdgcn_mfma_f32_32x32x16_bf16(ahA, blo0[s], aA0, 0, 0, 0);
                aA0 = __builtin_amdgcn_mfma_f32_32x32x16_bf16(alA, bhi0[s], aA0, 0, 0, 0);
                aA1 = __builtin_amdgcn_mfma_f32_32x32x16_bf16(ahA, bhi1[s], aA1, 0, 0, 0);
                aA1 = __builtin_amdgcn_mfma_f32_32x32x16_bf16(ahA, blo1[s], aA1, 0, 0, 0);
                aA1 = __builtin_amdgcn_mfma_f32_32x32x16_bf16(alA, bhi1[s], aA1, 0, 0, 0);
                aB0 = __builtin_amdgcn_mfma_f32_32x32x16_bf16(ahB, bhi0[s], aB0, 0, 0, 0);
                aB0 = __builtin_amdgcn_mfma_f32_32x32x16_bf16(ahB, blo0[s], aB0, 0, 0, 0);
                aB0 = __builtin_amdgcn_mfma_f32_32x32x16_bf16(alB, bhi0[s], aB0, 0, 0, 0);
                aB1 = __builtin_amdgcn_mfma_f32_32x32x16_bf16(ahB, bhi1[s], aB1, 0, 0, 0);
                aB1 = __builtin_amdgcn_mfma_f32_32x32x16_bf16(ahB, blo1[s], aB1, 0, 0, 0);
                aB1 = __builtin_amdgcn_mfma_f32_32x32x16_bf16(alB, bhi1[s], aB1, 0, 0, 0);
            }
            // c-fold pass LAST (keeps b-accumulation roundings at small magnitude):
            // adds 3.0 + bf16(c_row) to every column.
            bf16x8 cfA, cfB;
#pragma unroll
            for (int j = 0; j < 8; ++j) { cfA[j] = 0; cfB[j] = 0; }
            cfA[0] = (short)0x4040; cfA[1] = (short)lds_cb[c0];
            cfB[0] = (short)0x4040; cfB[1] = (short)lds_cb[c0 + 32];
            aA0 = __builtin_amdgcn_mfma_f32_32x32x16_bf16(cfA, ones, aA0, 0, 0, 0);
            aA1 = __builtin_amdgcn_mfma_f32_32x32x16_bf16(cfA, ones, aA1, 0, 0, 0);
            aB0 = __builtin_amdgcn_mfma_f32_32x32x16_bf16(cfB, ones, aB0, 0, 0, 0);
            aB1 = __builtin_amdgcn_mfma_f32_32x32x16_bf16(cfB, ones, aB1, 0, 0, 0);

            // epilogue: monotone bit-key = (bits(s_hat)<<7) + row_in_chunk.
            // s_hat in (2,4) for sane tokens => (bits-0x40000000)<<7 wraps exactly.
            const int rbase = tp * 64 + 4 * h;
#pragma unroll
            for (int r = 0; r < 16; ++r) {
                const unsigned int rcA = (unsigned int)(rbase + (r & 3) + 8 * (r >> 2));
                const unsigned int rcB = rcA + 32u;
                unsigned int key, mx;
                key = (__float_as_uint(aA0[r]) << 7) + rcA;
                mx = key > k10 ? key : k10; k10 = key < k10 ? key : k10; k20 = mx < k20 ? mx : k20;
                key = (__float_as_uint(aB0[r]) << 7) + rcB;
                mx = key > k10 ? key : k10; k10 = key < k10 ? key : k10; k20 = mx < k20 ? mx : k20;
                key = (__float_as_uint(aA1[r]) << 7) + rcA;
                mx = key > k11 ? key : k11; k11 = key < k11 ? key : k11; k21 = mx < k21 ? mx : k21;
                key = (__float_as_uint(aB1[r]) << 7) + rcB;
                mx = key > k11 ? key : k11; k11 = key < k11 ? key : k11; k21 = mx < k21 ? mx : k21;
            }
        }

        // fold chunk trackers into global (ascending cb => first-min-wins)
        {
            unsigned int cm = k10 >> 7, cc = (k10 & 127u) + (unsigned int)cb, c2 = k20 >> 7;
            unsigned int hi1 = cm > g1m0 ? cm : g1m0;
            unsigned int lo2 = c2 < g2m0 ? c2 : g2m0;
            g2m0 = hi1 < lo2 ? hi1 : lo2;
            if (cm < g1m0 || (cm == g1m0 && cc < g1c0)) { g1m0 = cm; g1c0 = cc; }
        }
        {
            unsigned int cm = k11 >> 7, cc = (k11 & 127u) + (unsigned int)cb, c2 = k21 >> 7;
            unsigned int hi1 = cm > g1m1 ? cm : g1m1;
            unsigned int lo2 = c2 < g2m1 ? c2 : g2m1;
            g2m1 = hi1 < lo2 ? hi1 : lo2;
            if (cm < g1m1 || (cm == g1m1 && cc < g1c1)) { g1m1 = cm; g1c1 = cc; }
        }
    }

    // ---- merge the two k-halves (lanes l and l^32 hold complementary rows)
    const unsigned int o1m0 = __shfl_xor(g1m0, 32, 64);
    const unsigned int o1c0 = __shfl_xor(g1c0, 32, 64);
    const unsigned int o2m0 = __shfl_xor(g2m0, 32, 64);
    const unsigned int o1m1 = __shfl_xor(g1m1, 32, 64);
    const unsigned int o1c1 = __shfl_xor(g1c1, 32, 64);
    const unsigned int o2m1 = __shfl_xor(g2m1, 32, 64);
    const float sax0 = sax0h + __shfl_xor(sax0h, 32, 64);
    const float sax1 = sax1h + __shfl_xor(sax1h, 32, 64);
    const float aa0  = a0h + __shfl_xor(a0h, 32, 64);
    const float aa1  = a1h + __shfl_xor(a1h, 32, 64);

    // h=0 lane decides token group 0; h=1 lane decides group 1
    const unsigned int a1m = h ? g1m1 : g1m0, a1c = h ? g1c1 : g1c0, a2m = h ? g2m1 : g2m0;
    const unsigned int b1m = h ? o1m1 : o1m0, b1c = h ? o1c1 : o1c0, b2m = h ? o2m1 : o2m0;
    const float sx = h ? sax1 : sax0;
    const float ax = h ? aa1 : aa0;
    const int tok = h ? tok1 : tok0;

    const unsigned int hi1 = a1m > b1m ? a1m : b1m;
    const unsigned int lo2 = a2m < b2m ? a2m : b2m;
    const unsigned int m2 = hi1 < lo2 ? hi1 : lo2;
    const bool bl = (b1m < a1m) || (b1m == a1m && b1c < a1c);
    const unsigned int m1 = bl ? b1m : a1m;
    const unsigned int c1 = bl ? b1c : a1c;

    const float s1 = __uint_as_float(0x40000000u + m1);
    const float s2 = __uint_as_float(0x40000000u + m2);
    // THR covers: bf16-split drop + MFMA accumulation (worst-case) + c-fold
    // roundings + the reference's own fl(a-2b), fl(+c) double rounding.
    const float thr = 3e-6f + 2.5e-7f * sx + 5e-7f * ax;
    const bool q = (s2 - s1 <= thr) || (sx >= 400.f) || (s1 < 2.5f) || (s1 > 3.5f);
    if (q) {
        unsigned int qi = atomicAdd(qcnt, 1u);
        if (qi < QCAP) queue[qi] = (unsigned int)tok;
    }
    out_idx[tok] = (float)c1;   // provisional for queued tokens; fallback overwrites
}

// exact reference replica for queued tokens: one wave per token, 16 codes/lane
__global__ __launch_bounds__(256) void vq_fallback_kernel(
    const float* __restrict__ in, const float* __restrict__ emb,
    const float* __restrict__ csum, const unsigned int* __restrict__ qcnt,
    const unsigned int* __restrict__ queue, float* __restrict__ out_idx) {
#pragma clang fp contract(off)
    unsigned int nq = *qcnt;
    if (nq > QCAP) nq = QCAP;
    const int l = threadIdx.x & 63;
    for (unsigned int w = blockIdx.x * 4 + (threadIdx.x >> 6); w < nq; w += 512) {
        const int tok = (int)queue[w];
        const float* xrow = in + (size_t)tok * E_DIM;
        float x[E_DIM];
#pragma unroll
        for (int j4 = 0; j4 < 16; ++j4) {
            const float4 u = *reinterpret_cast<const float4*>(xrow + j4 * 4);
            x[j4 * 4 + 0] = u.x; x[j4 * 4 + 1] = u.y;
            x[j4 * 4 + 2] = u.z; x[j4 * 4 + 3] = u.w;
        }
        // a: numpy AVX512 pairwise replica
        float s[16];
#pragma unroll
        for (int i = 0; i < 16; ++i)
            s[i] = (x[i] * x[i] + x[i + 16] * x[i + 16]) +
                   (x[i + 32] * x[i + 32] + x[i + 48] * x[i + 48]);
        float hh[8];
#pragma unroll
        for (int i = 0; i < 8; ++i) hh[i] = s[i] + s[i + 8];
        float uu[4];
#pragma unroll
        for (int i = 0; i < 4; ++i) uu[i] = hh[i] + hh[i + 4];
        const float a = (uu[0] + uu[2]) + (uu[1] + uu[3]);

        // b: single fmaf chain ascending k per code; d = (a - 2b) + c
        const int c0 = l * 16;
        float b[16];
#pragma unroll
        for (int q = 0; q < 16; ++q) b[q] = 0.f;
        for (int k = 0; k < E_DIM; ++k) {
            const float xk = x[k];
            const float* er = emb + k * N_EMBED + c0;
#pragma unroll
            for (int q = 0; q < 16; ++q) b[q] = fmaf(xk, er[q], b[q]);
        }
        float bd = 3.4e38f; int bi = 1 << 30;
#pragma unroll
        for (int q = 0; q < 16; ++q) {
            const float d = (a - 2.0f * b[q]) + csum[c0 + q];
            if (d < bd) { bd = d; bi = c0 + q; }
        }
        for (int m = 1; m < 64; m <<= 1) {
            const float od = __shfl_xor(bd, m, 64);
            const int oi = __shfl_xor(bi, m, 64);
            if (od < bd || (od == bd && oi < bi)) { bd = od; bi = oi; }
        }
        if (l == 0) out_idx[tok] = (float)bi;
    }
}

// quantize / input copy / straight-through grad (outputs 0..2), coalesced.
__global__ __launch_bounds__(256) void vq_gather_kernel(
    const float* __restrict__ in, const float* __restrict__ emb,
    const float* __restrict__ idxf,
    float* __restrict__ out_q, float* __restrict__ out_in, float* __restrict__ out_g) {
#pragma clang fp contract(off)
    const size_t j = (size_t)blockIdx.x * 256 + threadIdx.x;  // float4 index
    const int m  = (int)(j >> 4);
    const int k0 = ((int)j & 15) * 4;
    const int idx = (int)idxf[m];

    const float4 x = reinterpret_cast<const float4*>(in)[j];
    const float q0 = emb[(size_t)(k0 + 0) * N_EMBED + idx];
    const float q1 = emb[(size_t)(k0 + 1) * N_EMBED + idx];
    const float q2 = emb[(size_t)(k0 + 2) * N_EMBED + idx];
    const float q3 = emb[(size_t)(k0 + 3) * N_EMBED + idx];

    float4 q = make_float4(q0, q1, q2, q3);
    float4 g;
    g.x = x.x + (q0 - x.x);
    g.y = x.y + (q1 - x.y);
    g.z = x.z + (q2 - x.z);
    g.w = x.w + (q3 - x.w);

    reinterpret_cast<float4*>(out_q)[j]  = q;
    reinterpret_cast<float4*>(out_in)[j] = x;
    reinterpret_cast<float4*>(out_g)[j]  = g;
}

extern "C" void kernel_launch(void* const* d_in, const int* in_sizes, int n_in,
                              void* d_out, int out_size, void* d_ws, size_t ws_size,
                              hipStream_t stream) {
    const float* in  = (const float*)d_in[0];   // [262144, 64] f32
    const float* emb = (const float*)d_in[1];   // [64, 1024]  f32

    float* out     = (float*)d_out;
    float* out_q   = out;
    float* out_in  = out + (size_t)N_TOKENS * E_DIM;
    float* out_g   = out + 2ull * N_TOKENS * E_DIM;
    float* out_idx = out + 3ull * N_TOKENS * E_DIM;
    float* out_e   = out_idx + N_TOKENS;

    unsigned char* ws = (unsigned char*)d_ws;
    float*          c_ws  = (float*)(ws);                      // 4 KB
    unsigned short* cbf   = (unsigned short*)(ws + 4096);      // 2 KB
    short*          ehiT  = (short*)(ws + 8192);               // 128 KB
    short*          eloT  = (short*)(ws + 8192 + 131072);      // 128 KB
    unsigned int*   qcnt  = (unsigned int*)(ws + 8192 + 262144);
    unsigned int*   queue = (unsigned int*)(ws + 8192 + 262144 + 64);  // 256 KB

    hipMemsetAsync(qcnt, 0, sizeof(unsigned int), stream);

    vq_csum_kernel<<<4, 256, 0, stream>>>(emb, c_ws, cbf);
    vq_prep_split<<<256, 256, 0, stream>>>(emb, ehiT, eloT, out_e);

    vq_screen_kernel<<<N_TOKENS / 256, 256, 0, stream>>>(
        in, ehiT, eloT, cbf, out_idx, qcnt, queue);

    vq_fallback_kernel<<<128, 256, 0, stream>>>(in, emb, c_ws, qcnt, queue, out_idx);

    const int gather_blocks = (N_TOKENS * E_DIM / 4) / 256;    // 16384
    vq_gather_kernel<<<gather_blocks, 256, 0, stream>>>(in, emb, out_idx,
                                                        out_q, out_in, out_g);
}

// Round 5
// 505.534 us; speedup vs baseline: 1.8819x; 1.8819x over previous
//
#include <hip/hip_runtime.h>
#include <hip/hip_bf16.h>
#include <math.h>

#define E_DIM    64
#define N_EMBED  1024
#define N_TOKENS 262144
#define QCAP     65536

typedef __attribute__((ext_vector_type(8)))  short bf16x8;
typedef __attribute__((ext_vector_type(16))) float f32x16;

// ---------------------------------------------------------------------------
// Reference semantics (verified absmax 0.0 in rounds 2,3,4): f32 numpy mirror
//   b_j: single fmaf chain ascending k;  a: AVX512 pairwise;  c_j: sequential
//   dist = fl(fl(a - 2b) + c); argmin first-min-wins.
// Round 5 = round-3 geometry (32 tok/wave, 16 waves/CU) + round-4 MFMA c-fold
// and bit-key epilogue, extended to top-3 so near-ties are resolved INLINE
// (2 exact probes) and only 3-way ties (~0.1%) hit the fallback queue.
// ---------------------------------------------------------------------------

__device__ __forceinline__ short f2bf_bits(float f) {
    __hip_bfloat16 h = __float2bfloat16(f);
    return *reinterpret_cast<short*>(&h);
}
__device__ __forceinline__ float bfbits2f(short s) {
    unsigned int u = ((unsigned int)(unsigned short)s) << 16;
    return __uint_as_float(u);
}

// exact replica of one dist entry: d = fl(fl(a-2b)+c), b = fmaf chain asc k
__device__ __forceinline__ float exact_d(const float* __restrict__ xrow,
                                         const float* __restrict__ emb,
                                         const float* __restrict__ csum,
                                         float a, int j) {
#pragma clang fp contract(off)
    float b = 0.f;
#pragma unroll
    for (int k = 0; k < E_DIM; ++k) b = fmaf(xrow[k], emb[k * N_EMBED + j], b);
    return (a - 2.0f * b) + csum[j];
}

// c_j = sequential sum of e^2 (reference replica) + bf16(c) for the MFMA fold.
__global__ __launch_bounds__(256) void vq_csum_kernel(const float* __restrict__ emb,
                                                      float* __restrict__ c_out,
                                                      unsigned short* __restrict__ cbf) {
#pragma clang fp contract(off)
    const int j = blockIdx.x * 256 + threadIdx.x;
    if (j >= N_EMBED) return;
    float e = emb[j];
    float s = e * e;
    for (int k = 1; k < E_DIM; ++k) {
        float ek = emb[k * N_EMBED + j];
        float pk = ek * ek;
        s = s + pk;
    }
    c_out[j] = s;
    cbf[j] = (unsigned short)f2bf_bits(s);
}

// split -2*e into bf16 hi/lo, transposed to [code][k]; also emit embed copy.
__global__ __launch_bounds__(256) void vq_prep_split(const float* __restrict__ emb,
                                                     short* __restrict__ ehiT,
                                                     short* __restrict__ eloT,
                                                     float* __restrict__ out_e) {
    const int t = blockIdx.x * 256 + threadIdx.x;   // 0..65535
    const int k = t >> 10, n = t & 1023;
    float e = emb[t];
    float m2 = -2.0f * e;
    short hb = f2bf_bits(m2);
    float hf = bfbits2f(hb);
    short lb = f2bf_bits(m2 - hf);
    ehiT[n * E_DIM + k] = hb;
    eloT[n * E_DIM + k] = lb;
    out_e[t] = e;
}

__global__ __launch_bounds__(256, 4) void vq_screen_kernel(
    const float* __restrict__ in, const float* __restrict__ emb,
    const float* __restrict__ csum,
    const short* __restrict__ ehiT, const short* __restrict__ eloT,
    const unsigned short* __restrict__ cbf,
    float* __restrict__ out_idx,
    unsigned int* __restrict__ qcnt, unsigned int* __restrict__ queue)
{
    // slot-major LDS: [8 k-slots][128 codes] x 16B -> contiguous b128 r/w
    __shared__ uint4 lds_hi[8 * 128];
    __shared__ uint4 lds_lo[8 * 128];
    __shared__ unsigned short lds_cb[128];

    const int t = threadIdx.x;
    const int wave = t >> 6, l = t & 63, col = l & 31, h = l >> 5;
    const int tok = blockIdx.x * 128 + wave * 32 + col;
    const float* xrow = in + (size_t)tok * E_DIM;

    // ---- B operand (this lane's k-half): x[tok][s*16 + h*8 + j]
    float xv[4][8];
#pragma unroll
    for (int s = 0; s < 4; ++s) {
        float4 u0 = *reinterpret_cast<const float4*>(xrow + s * 16 + h * 8);
        float4 u1 = *reinterpret_cast<const float4*>(xrow + s * 16 + h * 8 + 4);
        xv[s][0] = u0.x; xv[s][1] = u0.y; xv[s][2] = u0.z; xv[s][3] = u0.w;
        xv[s][4] = u1.x; xv[s][5] = u1.y; xv[s][6] = u1.z; xv[s][7] = u1.w;
    }
    bf16x8 bhi[4], blo[4];
    float sax_h = 0.f;
#pragma unroll
    for (int s = 0; s < 4; ++s) {
#pragma unroll
        for (int j = 0; j < 8; ++j) {
            float x = xv[s][j];
            sax_h += fabsf(x);
            short hb = f2bf_bits(x);
            bhi[s][j] = hb;
            blo[s][j] = f2bf_bits(x - bfbits2f(hb));
        }
    }
    const float sax = sax_h + __shfl_xor(sax_h, 32, 64);

    // ---- exact a (AVX512-pairwise replica, verified rounds 2/3)
    float a_np;
    {
#pragma clang fp contract(off)
        float sv[8];
#pragma unroll
        for (int j = 0; j < 8; ++j) {
            float p0 = xv[0][j] * xv[0][j];
            float p1 = xv[1][j] * xv[1][j];
            float p2 = xv[2][j] * xv[2][j];
            float p3 = xv[3][j] * xv[3][j];
            sv[j] = (p0 + p1) + (p2 + p3);
        }
        float hh[8];
#pragma unroll
        for (int j = 0; j < 8; ++j) hh[j] = sv[j] + __shfl_xor(sv[j], 32, 64);
        float u0 = hh[0] + hh[4], u1 = hh[1] + hh[5];
        float u2 = hh[2] + hh[6], u3 = hh[3] + hh[7];
        a_np = (u0 + u2) + (u1 + u3);
    }

    // ones frag for the c-fold pass: B[k=0]=B[k=1]=1 (h=0 lanes), else 0
    bf16x8 ones;
#pragma unroll
    for (int j = 0; j < 8; ++j) ones[j] = 0;
    if (h == 0) { ones[0] = (short)0x3F80; ones[1] = (short)0x3F80; }

    // ---- global top-3 trackers: (value m, code c) lex for ranks 1,2; value for 3
    unsigned int gm1 = 0xFFFFFFFFu, gc1 = 1023u;
    unsigned int gm2 = 0xFFFFFFFFu, gc2 = 1023u;
    unsigned int gm3 = 0xFFFFFFFFu;

    for (int cb = 0; cb < N_EMBED; cb += 128) {
        __syncthreads();
        {   // stage 128 codes: threads 0-127 hi rows, 128-255 lo rows
            const int code = t & 127;
            const short* src = ((t < 128) ? ehiT : eloT) + (size_t)(cb + code) * E_DIM;
            uint4* dst = (t < 128) ? lds_hi : lds_lo;
            const uint4* s4 = reinterpret_cast<const uint4*>(src);
#pragma unroll
            for (int j = 0; j < 8; ++j) dst[j * 128 + code] = s4[j];
            if (t < 128) lds_cb[code] = cbf[cb + code];
        }
        __syncthreads();

        // per-chunk top-3 keys (key = bits(s_hat)<<7 | row_in_chunk, lex-exact)
        unsigned int k1 = 0xFFFFFFFFu, k2 = 0xFFFFFFFFu, k3 = 0xFFFFFFFFu;

#pragma unroll
        for (int tp = 0; tp < 2; ++tp) {
            const int c0 = tp * 64 + col;
            f32x16 accA, accB;
#pragma unroll
            for (int r = 0; r < 16; ++r) { accA[r] = 0.f; accB[r] = 0.f; }
#pragma unroll
            for (int s = 0; s < 4; ++s) {
                const int slot = 2 * s + h;
                bf16x8 ahA = *reinterpret_cast<const bf16x8*>(&lds_hi[slot * 128 + c0]);
                bf16x8 alA = *reinterpret_cast<const bf16x8*>(&lds_lo[slot * 128 + c0]);
                bf16x8 ahB = *reinterpret_cast<const bf16x8*>(&lds_hi[slot * 128 + c0 + 32]);
                bf16x8 alB = *reinterpret_cast<const bf16x8*>(&lds_lo[slot * 128 + c0 + 32]);
                accA = __builtin_amdgcn_mfma_f32_32x32x16_bf16(ahA, bhi[s], accA, 0, 0, 0);
                accB = __builtin_amdgcn_mfma_f32_32x32x16_bf16(ahB, bhi[s], accB, 0, 0, 0);
                accA = __builtin_amdgcn_mfma_f32_32x32x16_bf16(ahA, blo[s], accA, 0, 0, 0);
                accB = __builtin_amdgcn_mfma_f32_32x32x16_bf16(ahB, blo[s], accB, 0, 0, 0);
                accA = __builtin_amdgcn_mfma_f32_32x32x16_bf16(alA, bhi[s], accA, 0, 0, 0);
                accB = __builtin_amdgcn_mfma_f32_32x32x16_bf16(alB, bhi[s], accB, 0, 0, 0);
            }
            // c-fold LAST: acc += 3.0 + bf16(c_row)
            bf16x8 cfA, cfB;
#pragma unroll
            for (int j = 0; j < 8; ++j) { cfA[j] = 0; cfB[j] = 0; }
            cfA[0] = (short)0x4040; cfA[1] = (short)lds_cb[c0];
            cfB[0] = (short)0x4040; cfB[1] = (short)lds_cb[c0 + 32];
            accA = __builtin_amdgcn_mfma_f32_32x32x16_bf16(cfA, ones, accA, 0, 0, 0);
            accB = __builtin_amdgcn_mfma_f32_32x32x16_bf16(cfB, ones, accB, 0, 0, 0);

            const unsigned int rbase = (unsigned int)(tp * 64 + 4 * h);
#pragma unroll
            for (int r = 0; r < 16; ++r) {
                const unsigned int rc = rbase + (unsigned int)((r & 3) + 8 * (r >> 2));
                unsigned int key, mxa, mxb;
                key = (__float_as_uint(accA[r]) << 7) + rc;
                mxa = key > k1 ? key : k1;  k1 = key < k1 ? key : k1;
                mxb = mxa > k2 ? mxa : k2;  k2 = mxa < k2 ? mxa : k2;
                k3 = mxb < k3 ? mxb : k3;
                key = (__float_as_uint(accB[r]) << 7) + (rc + 32u);
                mxa = key > k1 ? key : k1;  k1 = key < k1 ? key : k1;
                mxb = mxa > k2 ? mxa : k2;  k2 = mxa < k2 ? mxa : k2;
                k3 = mxb < k3 ? mxb : k3;
            }
        }

        // merge chunk top-3 into global (ascending cb + lex => first-min-wins)
#pragma unroll
        for (int q3 = 0; q3 < 3; ++q3) {
            const unsigned int kk = (q3 == 0) ? k1 : (q3 == 1) ? k2 : k3;
            const unsigned int m = kk >> 7;
            const unsigned int c = (kk & 127u) + (unsigned int)cb;
            const bool lt1 = (m < gm1) || (m == gm1 && c < gc1);
            const bool lt2 = (m < gm2) || (m == gm2 && c < gc2);
            const bool lt3 = (m < gm3);
            gm3 = lt2 ? gm2 : (lt3 ? m : gm3);
            gm2 = lt1 ? gm1 : (lt2 ? m : gm2);
            gc2 = lt1 ? gc1 : (lt2 ? c : gc2);
            gm1 = lt1 ? m : gm1;
            gc1 = lt1 ? c : gc1;
        }
    }

    // ---- cross-half merge (lanes l, l^32 hold complementary rows of same token)
    {
        const unsigned int om1 = __shfl_xor(gm1, 32, 64);
        const unsigned int oc1 = __shfl_xor(gc1, 32, 64);
        const unsigned int om2 = __shfl_xor(gm2, 32, 64);
        const unsigned int oc2 = __shfl_xor(gc2, 32, 64);
        const unsigned int om3 = __shfl_xor(gm3, 32, 64);
#pragma unroll
        for (int q3 = 0; q3 < 3; ++q3) {
            const unsigned int m = (q3 == 0) ? om1 : (q3 == 1) ? om2 : om3;
            const unsigned int c = (q3 == 0) ? oc1 : (q3 == 1) ? oc2 : 0x7FFFFFFFu;
            const bool lt1 = (m < gm1) || (m == gm1 && c < gc1);
            const bool lt2 = (m < gm2) || (m == gm2 && c < gc2);
            const bool lt3 = (m < gm3);
            gm3 = lt2 ? gm2 : (lt3 ? m : gm3);
            gm2 = lt1 ? gm1 : (lt2 ? m : gm2);
            gc2 = lt1 ? gc1 : (lt2 ? c : gc2);
            gm1 = lt1 ? m : gm1;
            gc1 = lt1 ? c : gc1;
        }
    }

    if (h == 0) {
        const float s1 = __uint_as_float(0x40000000u + gm1);
        const float s2 = __uint_as_float(0x40000000u + gm2);
        const float s3 = __uint_as_float(0x40000000u + gm3);
        // THR: screen err (lo*lo drop + MFMA accum + c-fold + bf16(c)) <= ~2e-6
        //      + reference double-rounding 2*ulp(<=150) <= 3.1e-5; margin 1.3x.
        const float thr = 4e-5f + 1e-7f * sax;
        // a in [20,150] => |2b| <= 0.11 => s_hat in [2.87,3.13]: no key wrap.
        const bool sane = (a_np > 20.f) && (a_np < 150.f) &&
                          (s1 > 2.5f) && (s1 < 3.5f);
        int fin = (int)gc1;
        if (sane && (s2 - s1 > thr)) {
            // certified: screen winner = reference argmin
        } else if (sane && (s3 - s1 > thr)) {
            // true argmin is one of {gc1, gc2}: exact pair resolve (lex)
            const float d1 = exact_d(xrow, emb, csum, a_np, (int)gc1);
            const float d2 = exact_d(xrow, emb, csum, a_np, (int)gc2);
            if (d2 < d1 || (d2 == d1 && gc2 < gc1)) fin = (int)gc2;
        } else {
            const unsigned int qi = atomicAdd(qcnt, 1u);
            if (qi < QCAP) queue[qi] = (unsigned int)tok;
            // provisional fin = gc1; fallback overwrites
        }
        out_idx[tok] = (float)fin;
    }
}

// exact reference replica for queued tokens: one wave per token, 16 codes/lane
__global__ __launch_bounds__(256) void vq_fallback_kernel(
    const float* __restrict__ in, const float* __restrict__ emb,
    const float* __restrict__ csum, const unsigned int* __restrict__ qcnt,
    const unsigned int* __restrict__ queue, float* __restrict__ out_idx) {
#pragma clang fp contract(off)
    unsigned int nq = *qcnt;
    if (nq > QCAP) nq = QCAP;
    const int l = threadIdx.x & 63;
    for (unsigned int w = blockIdx.x * 4 + (threadIdx.x >> 6); w < nq; w += 1024) {
        const int tok = (int)queue[w];
        const float* xrow = in + (size_t)tok * E_DIM;
        float x[E_DIM];
#pragma unroll
        for (int j4 = 0; j4 < 16; ++j4) {
            const float4 u = *reinterpret_cast<const float4*>(xrow + j4 * 4);
            x[j4 * 4 + 0] = u.x; x[j4 * 4 + 1] = u.y;
            x[j4 * 4 + 2] = u.z; x[j4 * 4 + 3] = u.w;
        }
        float s[16];
#pragma unroll
        for (int i = 0; i < 16; ++i)
            s[i] = (x[i] * x[i] + x[i + 16] * x[i + 16]) +
                   (x[i + 32] * x[i + 32] + x[i + 48] * x[i + 48]);
        float hh[8];
#pragma unroll
        for (int i = 0; i < 8; ++i) hh[i] = s[i] + s[i + 8];
        float uu[4];
#pragma unroll
        for (int i = 0; i < 4; ++i) uu[i] = hh[i] + hh[i + 4];
        const float a = (uu[0] + uu[2]) + (uu[1] + uu[3]);

        const int c0 = l * 16;
        float b[16];
#pragma unroll
        for (int q = 0; q < 16; ++q) b[q] = 0.f;
        for (int k = 0; k < E_DIM; ++k) {
            const float xk = x[k];
            const float* er = emb + k * N_EMBED + c0;
#pragma unroll
            for (int q = 0; q < 16; ++q) b[q] = fmaf(xk, er[q], b[q]);
        }
        float bd = 3.4e38f; int bi = 1 << 30;
#pragma unroll
        for (int q = 0; q < 16; ++q) {
            const float d = (a - 2.0f * b[q]) + csum[c0 + q];
            if (d < bd) { bd = d; bi = c0 + q; }
        }
        for (int m = 1; m < 64; m <<= 1) {
            const float od = __shfl_xor(bd, m, 64);
            const int oi = __shfl_xor(bi, m, 64);
            if (od < bd || (od == bd && oi < bi)) { bd = od; bi = oi; }
        }
        if (l == 0) out_idx[tok] = (float)bi;
    }
}

// quantize / input copy / straight-through grad (outputs 0..2), coalesced.
__global__ __launch_bounds__(256) void vq_gather_kernel(
    const float* __restrict__ in, const float* __restrict__ emb,
    const float* __restrict__ idxf,
    float* __restrict__ out_q, float* __restrict__ out_in, float* __restrict__ out_g) {
#pragma clang fp contract(off)
    const size_t j = (size_t)blockIdx.x * 256 + threadIdx.x;  // float4 index
    const int m  = (int)(j >> 4);
    const int k0 = ((int)j & 15) * 4;
    const int idx = (int)idxf[m];

    const float4 x = reinterpret_cast<const float4*>(in)[j];
    const float q0 = emb[(size_t)(k0 + 0) * N_EMBED + idx];
    const float q1 = emb[(size_t)(k0 + 1) * N_EMBED + idx];
    const float q2 = emb[(size_t)(k0 + 2) * N_EMBED + idx];
    const float q3 = emb[(size_t)(k0 + 3) * N_EMBED + idx];

    float4 q = make_float4(q0, q1, q2, q3);
    float4 g;
    g.x = x.x + (q0 - x.x);
    g.y = x.y + (q1 - x.y);
    g.z = x.z + (q2 - x.z);
    g.w = x.w + (q3 - x.w);

    reinterpret_cast<float4*>(out_q)[j]  = q;
    reinterpret_cast<float4*>(out_in)[j] = x;
    reinterpret_cast<float4*>(out_g)[j]  = g;
}

extern "C" void kernel_launch(void* const* d_in, const int* in_sizes, int n_in,
                              void* d_out, int out_size, void* d_ws, size_t ws_size,
                              hipStream_t stream) {
    const float* in  = (const float*)d_in[0];   // [262144, 64] f32
    const float* emb = (const float*)d_in[1];   // [64, 1024]  f32

    float* out     = (float*)d_out;
    float* out_q   = out;
    float* out_in  = out + (size_t)N_TOKENS * E_DIM;
    float* out_g   = out + 2ull * N_TOKENS * E_DIM;
    float* out_idx = out + 3ull * N_TOKENS * E_DIM;
    float* out_e   = out_idx + N_TOKENS;

    unsigned char* ws = (unsigned char*)d_ws;
    float*          c_ws  = (float*)(ws);                      // 4 KB
    unsigned short* cbf   = (unsigned short*)(ws + 4096);      // 2 KB
    short*          ehiT  = (short*)(ws + 8192);               // 128 KB
    short*          eloT  = (short*)(ws + 8192 + 131072);      // 128 KB
    unsigned int*   qcnt  = (unsigned int*)(ws + 8192 + 262144);
    unsigned int*   queue = (unsigned int*)(ws + 8192 + 262144 + 64);  // 256 KB

    hipMemsetAsync(qcnt, 0, sizeof(unsigned int), stream);

    vq_csum_kernel<<<4, 256, 0, stream>>>(emb, c_ws, cbf);
    vq_prep_split<<<256, 256, 0, stream>>>(emb, ehiT, eloT, out_e);

    vq_screen_kernel<<<N_TOKENS / 128, 256, 0, stream>>>(
        in, emb, c_ws, ehiT, eloT, cbf, out_idx, qcnt, queue);

    vq_fallback_kernel<<<256, 256, 0, stream>>>(in, emb, c_ws, qcnt, queue, out_idx);

    const int gather_blocks = (N_TOKENS * E_DIM / 4) / 256;    // 16384
    vq_gather_kernel<<<gather_blocks, 256, 0, stream>>>(in, emb, out_idx,
                                                        out_q, out_in, out_g);
}

// Round 6
// 476.137 us; speedup vs baseline: 1.9981x; 1.0617x over previous
//
#include <hip/hip_runtime.h>
#include <hip/hip_bf16.h>
#include <math.h>

#define E_DIM    64
#define N_EMBED  1024
#define N_TOKENS 262144
#define PQCAP    65536
#define FQCAP    16384

typedef __attribute__((ext_vector_type(8)))  short bf16x8;
typedef __attribute__((ext_vector_type(16))) float f32x16;

// ---------------------------------------------------------------------------
// Reference semantics (verified absmax 0.0 in rounds 2-5): f32 numpy mirror
//   b_j: single fmaf chain ascending k;  a: AVX512 pairwise;  c_j: sequential
//   dist = fl(fl(a - 2b) + c); argmin first-min-wins.
// Round 6: register-diet screen (MFMA 3-pass bf16 split + c-fold, bit-key
// top-3, NO inline exact math) + pair-resolve kernel (~1-2% tokens, 2 exact
// probes each) + full-rescan kernel (3-way ties / guards, ~1e-4 of tokens).
// Spill fix: moved exact_d/a_np out of screen, launch_bounds(256,3).
// ---------------------------------------------------------------------------

__device__ __forceinline__ short f2bf_bits(float f) {
    __hip_bfloat16 h = __float2bfloat16(f);
    return *reinterpret_cast<short*>(&h);
}
__device__ __forceinline__ float bfbits2f(short s) {
    unsigned int u = ((unsigned int)(unsigned short)s) << 16;
    return __uint_as_float(u);
}

// a = np.sum(x*x, axis=1) replica (AVX512 pairwise), x in registers
__device__ __forceinline__ float a_np_of(const float* x) {
#pragma clang fp contract(off)
    float s[16];
#pragma unroll
    for (int i = 0; i < 16; ++i)
        s[i] = (x[i] * x[i] + x[i + 16] * x[i + 16]) +
               (x[i + 32] * x[i + 32] + x[i + 48] * x[i + 48]);
    float hh[8];
#pragma unroll
    for (int i = 0; i < 8; ++i) hh[i] = s[i] + s[i + 8];
    float uu[4];
#pragma unroll
    for (int i = 0; i < 4; ++i) uu[i] = hh[i] + hh[i + 4];
    return (uu[0] + uu[2]) + (uu[1] + uu[3]);
}

// c_j = sequential sum of e^2 (reference replica) + bf16(c) for the MFMA fold.
__global__ __launch_bounds__(256) void vq_csum_kernel(const float* __restrict__ emb,
                                                      float* __restrict__ c_out,
                                                      unsigned short* __restrict__ cbf) {
#pragma clang fp contract(off)
    const int j = blockIdx.x * 256 + threadIdx.x;
    if (j >= N_EMBED) return;
    float e = emb[j];
    float s = e * e;
    for (int k = 1; k < E_DIM; ++k) {
        float ek = emb[k * N_EMBED + j];
        float pk = ek * ek;
        s = s + pk;
    }
    c_out[j] = s;
    cbf[j] = (unsigned short)f2bf_bits(s);
}

// split -2*e into bf16 hi/lo in the screen's LDS-linear chunk layout:
// eTc[chunk][hi=0/lo=1][slot=k>>3][code][j=k&7], chunk = 16384 shorts (32 KB).
// Also emits the embed passthrough output.
__global__ __launch_bounds__(256) void vq_prep_split(const float* __restrict__ emb,
                                                     short* __restrict__ eTc,
                                                     float* __restrict__ out_e) {
    const int t = blockIdx.x * 256 + threadIdx.x;   // t = k*1024 + n
    const int k = t >> 10, n = t & 1023;
    float e = emb[t];
    float m2 = -2.0f * e;
    short hb = f2bf_bits(m2);
    float hf = bfbits2f(hb);
    short lb = f2bf_bits(m2 - hf);
    const int chunk = n >> 7, code = n & 127, slot = k >> 3, jj = k & 7;
    const int base = chunk * 16384 + (slot * 128 + code) * 8 + jj;
    eTc[base]        = hb;
    eTc[base + 8192] = lb;
    out_e[t] = e;
}

__global__ __launch_bounds__(256, 3) void vq_screen_kernel(
    const float* __restrict__ in, const short* __restrict__ eTc,
    const unsigned short* __restrict__ cbf,
    float* __restrict__ out_idx, unsigned int* __restrict__ qcnt,
    uint2* __restrict__ pairQ, unsigned int* __restrict__ fullQ)
{
    __shared__ uint4 lds_e[2048];   // [0..1024) hi, [1024..2048) lo ; 32 KB

    const int t = threadIdx.x;
    const int wave = t >> 6, l = t & 63, col = l & 31, h = l >> 5;
    const int tok = blockIdx.x * 128 + wave * 32 + col;
    const float* xrow = in + (size_t)tok * E_DIM;

    // ---- B operand (this lane's k-half) + sum|x|
    bf16x8 bhi[4], blo[4];
    float sax_h = 0.f;
#pragma unroll
    for (int s = 0; s < 4; ++s) {
        float4 u0 = *reinterpret_cast<const float4*>(xrow + s * 16 + h * 8);
        float4 u1 = *reinterpret_cast<const float4*>(xrow + s * 16 + h * 8 + 4);
        float xs[8] = {u0.x, u0.y, u0.z, u0.w, u1.x, u1.y, u1.z, u1.w};
#pragma unroll
        for (int j = 0; j < 8; ++j) {
            float x = xs[j];
            sax_h += fabsf(x);
            short hb = f2bf_bits(x);
            bhi[s][j] = hb;
            blo[s][j] = f2bf_bits(x - bfbits2f(hb));
        }
    }
    const float sax = sax_h + __shfl_xor(sax_h, 32, 64);

    // ones frag for the c-fold pass: B[k=0]=B[k=1]=1 (h=0 lanes supply k=0..7)
    bf16x8 ones;
#pragma unroll
    for (int j = 0; j < 8; ++j) ones[j] = 0;
    if (h == 0) { ones[0] = (short)0x3F80; ones[1] = (short)0x3F80; }

    // global top-3: (m, code) lex for ranks 1,2; m for rank 3
    unsigned int gm1 = 0xFFFFFFFFu, gc1 = 1023u;
    unsigned int gm2 = 0xFFFFFFFFu, gc2 = 1023u;
    unsigned int gm3 = 0xFFFFFFFFu;

    for (int cc = 0; cc < 8; ++cc) {
        __syncthreads();
        {   // linear 32 KB copy: coalesced global, conflict-free b128 LDS writes
            const uint4* gsrc = reinterpret_cast<const uint4*>(eTc) + cc * 2048;
#pragma unroll
            for (int j = 0; j < 8; ++j) lds_e[j * 256 + t] = gsrc[j * 256 + t];
        }
        __syncthreads();

        const int cb = cc << 7;
        unsigned int k1 = 0xFFFFFFFFu, k2 = 0xFFFFFFFFu, k3 = 0xFFFFFFFFu;

#pragma unroll
        for (int tp = 0; tp < 2; ++tp) {
            const int c0 = tp * 64 + col;
            f32x16 accA, accB;
#pragma unroll
            for (int r = 0; r < 16; ++r) { accA[r] = 0.f; accB[r] = 0.f; }
#pragma unroll
            for (int s = 0; s < 4; ++s) {
                const int slot = 2 * s + h;
                bf16x8 ahA = *reinterpret_cast<const bf16x8*>(&lds_e[slot * 128 + c0]);
                bf16x8 alA = *reinterpret_cast<const bf16x8*>(&lds_e[1024 + slot * 128 + c0]);
                bf16x8 ahB = *reinterpret_cast<const bf16x8*>(&lds_e[slot * 128 + c0 + 32]);
                bf16x8 alB = *reinterpret_cast<const bf16x8*>(&lds_e[1024 + slot * 128 + c0 + 32]);
                accA = __builtin_amdgcn_mfma_f32_32x32x16_bf16(ahA, bhi[s], accA, 0, 0, 0);
                accB = __builtin_amdgcn_mfma_f32_32x32x16_bf16(ahB, bhi[s], accB, 0, 0, 0);
                accA = __builtin_amdgcn_mfma_f32_32x32x16_bf16(ahA, blo[s], accA, 0, 0, 0);
                accB = __builtin_amdgcn_mfma_f32_32x32x16_bf16(ahB, blo[s], accB, 0, 0, 0);
                accA = __builtin_amdgcn_mfma_f32_32x32x16_bf16(alA, bhi[s], accA, 0, 0, 0);
                accB = __builtin_amdgcn_mfma_f32_32x32x16_bf16(alB, bhi[s], accB, 0, 0, 0);
            }
            // c-fold LAST: acc += 3.0 + bf16(c_row); h=1 lanes' A values hit B=0.
            bf16x8 cfA, cfB;
#pragma unroll
            for (int j = 0; j < 8; ++j) { cfA[j] = 0; cfB[j] = 0; }
            cfA[0] = (short)0x4040; cfA[1] = (short)cbf[cb + c0];
            cfB[0] = (short)0x4040; cfB[1] = (short)cbf[cb + c0 + 32];
            accA = __builtin_amdgcn_mfma_f32_32x32x16_bf16(cfA, ones, accA, 0, 0, 0);
            accB = __builtin_amdgcn_mfma_f32_32x32x16_bf16(cfB, ones, accB, 0, 0, 0);

            // bit-key top-3: key = (bits(s_hat)<<7)+row, exact lex for s_hat in [2,4)
            const unsigned int rbase = (unsigned int)(tp * 64 + 4 * h);
#pragma unroll
            for (int r = 0; r < 16; ++r) {
                const unsigned int rc = rbase + (unsigned int)((r & 3) + 8 * (r >> 2));
                unsigned int key, mxa, mxb;
                key = (__float_as_uint(accA[r]) << 7) + rc;
                mxa = key > k1 ? key : k1;  k1 = key < k1 ? key : k1;
                mxb = mxa > k2 ? mxa : k2;  k2 = mxa < k2 ? mxa : k2;
                k3 = mxb < k3 ? mxb : k3;
                key = (__float_as_uint(accB[r]) << 7) + (rc + 32u);
                mxa = key > k1 ? key : k1;  k1 = key < k1 ? key : k1;
                mxb = mxa > k2 ? mxa : k2;  k2 = mxa < k2 ? mxa : k2;
                k3 = mxb < k3 ? mxb : k3;
            }
        }

        // merge chunk top-3 into global (ascending cb + lex => first-min-wins)
#pragma unroll
        for (int q3 = 0; q3 < 3; ++q3) {
            const unsigned int kk = (q3 == 0) ? k1 : (q3 == 1) ? k2 : k3;
            const unsigned int m = kk >> 7;
            const unsigned int c = (kk & 127u) + (unsigned int)cb;
            const bool lt1 = (m < gm1) || (m == gm1 && c < gc1);
            const bool lt2 = (m < gm2) || (m == gm2 && c < gc2);
            const bool lt3 = (m < gm3);
            gm3 = lt2 ? gm2 : (lt3 ? m : gm3);
            gm2 = lt1 ? gm1 : (lt2 ? m : gm2);
            gc2 = lt1 ? gc1 : (lt2 ? c : gc2);
            gm1 = lt1 ? m : gm1;
            gc1 = lt1 ? c : gc1;
        }
    }

    // ---- cross-half merge (lanes l, l^32 hold complementary rows of same token)
    {
        const unsigned int om1 = __shfl_xor(gm1, 32, 64);
        const unsigned int oc1 = __shfl_xor(gc1, 32, 64);
        const unsigned int om2 = __shfl_xor(gm2, 32, 64);
        const unsigned int oc2 = __shfl_xor(gc2, 32, 64);
        const unsigned int om3 = __shfl_xor(gm3, 32, 64);
#pragma unroll
        for (int q3 = 0; q3 < 3; ++q3) {
            const unsigned int m = (q3 == 0) ? om1 : (q3 == 1) ? om2 : om3;
            const unsigned int c = (q3 == 0) ? oc1 : (q3 == 1) ? oc2 : 0x7FFFFFFFu;
            const bool lt1 = (m < gm1) || (m == gm1 && c < gc1);
            const bool lt2 = (m < gm2) || (m == gm2 && c < gc2);
            const bool lt3 = (m < gm3);
            gm3 = lt2 ? gm2 : (lt3 ? m : gm3);
            gm2 = lt1 ? gm1 : (lt2 ? m : gm2);
            gc2 = lt1 ? gc1 : (lt2 ? c : gc2);
            gm1 = lt1 ? m : gm1;
            gc1 = lt1 ? c : gc1;
        }
    }

    if (h == 0) {
        const float s1 = __uint_as_float(0x40000000u + gm1);
        const float s2 = __uint_as_float(0x40000000u + gm2);
        const float s3 = __uint_as_float(0x40000000u + gm3);
        // screen err (<=~4e-6) + reference fl(a-2b),fl(+c) double rounding
        // (<=~8e-6): thr = 2x sum with margin.
        const float thr = 4e-5f + 1e-7f * sax;
        // sax<128 => |2b|<=0.25 => every s_hat in [2.75,3.25]: no key wrap.
        const bool sane = (sax < 128.f) && (s1 > 2.5f) && (s1 < 3.5f);
        if (!sane || (s3 - s1 <= thr)) {
            const unsigned int qi = atomicAdd(&qcnt[1], 1u);
            if (qi < FQCAP) fullQ[qi] = (unsigned int)tok;
        } else if (s2 - s1 <= thr) {
            const unsigned int qi = atomicAdd(&qcnt[0], 1u);
            if (qi < PQCAP) pairQ[qi] = make_uint2((unsigned int)tok, gc1 | (gc2 << 16));
        }
        out_idx[tok] = (float)gc1;  // provisional for queued tokens
    }
}

// pair resolve: exact reference replica for the 2 candidate codes, 1 thread/token
__global__ __launch_bounds__(256) void vq_pair_kernel(
    const float* __restrict__ in, const float* __restrict__ emb,
    const float* __restrict__ csum, const unsigned int* __restrict__ qcnt,
    const uint2* __restrict__ pairQ, float* __restrict__ out_idx) {
#pragma clang fp contract(off)
    unsigned int nq = qcnt[0];
    if (nq > PQCAP) nq = PQCAP;
    for (unsigned int i = blockIdx.x * 256 + threadIdx.x; i < nq; i += 64 * 256) {
        const uint2 e = pairQ[i];
        const int tok = (int)e.x;
        const int c1 = (int)(e.y & 0xFFFFu), c2 = (int)(e.y >> 16);
        const float* xrow = in + (size_t)tok * E_DIM;
        float x[E_DIM];
#pragma unroll
        for (int j4 = 0; j4 < 16; ++j4) {
            const float4 u = *reinterpret_cast<const float4*>(xrow + j4 * 4);
            x[j4 * 4 + 0] = u.x; x[j4 * 4 + 1] = u.y;
            x[j4 * 4 + 2] = u.z; x[j4 * 4 + 3] = u.w;
        }
        const float a = a_np_of(x);
        float b1 = 0.f, b2 = 0.f;
        for (int k = 0; k < E_DIM; ++k) {
            const float xk = x[k];
            b1 = fmaf(xk, emb[k * N_EMBED + c1], b1);
            b2 = fmaf(xk, emb[k * N_EMBED + c2], b2);
        }
        const float d1 = (a - 2.0f * b1) + csum[c1];
        const float d2 = (a - 2.0f * b2) + csum[c2];
        int fin = c1;
        if (d2 < d1 || (d2 == d1 && c2 < c1)) fin = c2;
        out_idx[tok] = (float)fin;
    }
}

// exact full rescan (reference replica) for 3-way ties / guard trips
__global__ __launch_bounds__(256) void vq_full_kernel(
    const float* __restrict__ in, const float* __restrict__ emb,
    const float* __restrict__ csum, const unsigned int* __restrict__ qcnt,
    const unsigned int* __restrict__ fullQ, float* __restrict__ out_idx) {
#pragma clang fp contract(off)
    unsigned int nq = qcnt[1];
    if (nq > FQCAP) nq = FQCAP;
    const int l = threadIdx.x & 63;
    for (unsigned int w = blockIdx.x * 4 + (threadIdx.x >> 6); w < nq; w += 128) {
        const int tok = (int)fullQ[w];
        const float* xrow = in + (size_t)tok * E_DIM;
        float x[E_DIM];
#pragma unroll
        for (int j4 = 0; j4 < 16; ++j4) {
            const float4 u = *reinterpret_cast<const float4*>(xrow + j4 * 4);
            x[j4 * 4 + 0] = u.x; x[j4 * 4 + 1] = u.y;
            x[j4 * 4 + 2] = u.z; x[j4 * 4 + 3] = u.w;
        }
        const float a = a_np_of(x);
        const int c0 = l * 16;
        float b[16];
#pragma unroll
        for (int q = 0; q < 16; ++q) b[q] = 0.f;
        for (int k = 0; k < E_DIM; ++k) {
            const float xk = x[k];
            const float* er = emb + k * N_EMBED + c0;
#pragma unroll
            for (int q = 0; q < 16; ++q) b[q] = fmaf(xk, er[q], b[q]);
        }
        float bd = 3.4e38f; int bi = 1 << 30;
#pragma unroll
        for (int q = 0; q < 16; ++q) {
            const float d = (a - 2.0f * b[q]) + csum[c0 + q];
            if (d < bd) { bd = d; bi = c0 + q; }
        }
        for (int m = 1; m < 64; m <<= 1) {
            const float od = __shfl_xor(bd, m, 64);
            const int oi = __shfl_xor(bi, m, 64);
            if (od < bd || (od == bd && oi < bi)) { bd = od; bi = oi; }
        }
        if (l == 0) out_idx[tok] = (float)bi;
    }
}

// quantize / input copy / straight-through grad (outputs 0..2), coalesced.
__global__ __launch_bounds__(256) void vq_gather_kernel(
    const float* __restrict__ in, const float* __restrict__ emb,
    const float* __restrict__ idxf,
    float* __restrict__ out_q, float* __restrict__ out_in, float* __restrict__ out_g) {
#pragma clang fp contract(off)
    const size_t j = (size_t)blockIdx.x * 256 + threadIdx.x;  // float4 index
    const int m  = (int)(j >> 4);
    const int k0 = ((int)j & 15) * 4;
    const int idx = (int)idxf[m];

    const float4 x = reinterpret_cast<const float4*>(in)[j];
    const float q0 = emb[(size_t)(k0 + 0) * N_EMBED + idx];
    const float q1 = emb[(size_t)(k0 + 1) * N_EMBED + idx];
    const float q2 = emb[(size_t)(k0 + 2) * N_EMBED + idx];
    const float q3 = emb[(size_t)(k0 + 3) * N_EMBED + idx];

    float4 q = make_float4(q0, q1, q2, q3);
    float4 g;
    g.x = x.x + (q0 - x.x);
    g.y = x.y + (q1 - x.y);
    g.z = x.z + (q2 - x.z);
    g.w = x.w + (q3 - x.w);

    reinterpret_cast<float4*>(out_q)[j]  = q;
    reinterpret_cast<float4*>(out_in)[j] = x;
    reinterpret_cast<float4*>(out_g)[j]  = g;
}

extern "C" void kernel_launch(void* const* d_in, const int* in_sizes, int n_in,
                              void* d_out, int out_size, void* d_ws, size_t ws_size,
                              hipStream_t stream) {
    const float* in  = (const float*)d_in[0];   // [262144, 64] f32
    const float* emb = (const float*)d_in[1];   // [64, 1024]  f32

    float* out     = (float*)d_out;
    float* out_q   = out;
    float* out_in  = out + (size_t)N_TOKENS * E_DIM;
    float* out_g   = out + 2ull * N_TOKENS * E_DIM;
    float* out_idx = out + 3ull * N_TOKENS * E_DIM;
    float* out_e   = out_idx + N_TOKENS;

    unsigned char* ws = (unsigned char*)d_ws;
    float*          c_ws  = (float*)(ws);                        // 4 KB
    unsigned short* cbf   = (unsigned short*)(ws + 4096);        // 2 KB
    short*          eTc   = (short*)(ws + 8192);                 // 256 KB
    unsigned int*   qcnt  = (unsigned int*)(ws + 8192 + 262144); // 256 B pad
    uint2*          pairQ = (uint2*)(ws + 8192 + 262144 + 256);  // 512 KB
    unsigned int*   fullQ = (unsigned int*)(ws + 8192 + 262144 + 256 + PQCAP * 8); // 64 KB

    hipMemsetAsync(qcnt, 0, 2 * sizeof(unsigned int), stream);

    vq_csum_kernel<<<4, 256, 0, stream>>>(emb, c_ws, cbf);
    vq_prep_split<<<256, 256, 0, stream>>>(emb, eTc, out_e);

    vq_screen_kernel<<<N_TOKENS / 128, 256, 0, stream>>>(
        in, eTc, cbf, out_idx, qcnt, pairQ, fullQ);

    vq_pair_kernel<<<64, 256, 0, stream>>>(in, emb, c_ws, qcnt, pairQ, out_idx);
    vq_full_kernel<<<32, 256, 0, stream>>>(in, emb, c_ws, qcnt, fullQ, out_idx);

    const int gather_blocks = (N_TOKENS * E_DIM / 4) / 256;      // 16384
    vq_gather_kernel<<<gather_blocks, 256, 0, stream>>>(in, emb, out_idx,
                                                        out_q, out_in, out_g);
}

// Round 8
// 308.470 us; speedup vs baseline: 3.0842x; 1.5435x over previous
//
#include <hip/hip_runtime.h>
#include <hip/hip_bf16.h>
#include <math.h>

#define E_DIM    64
#define N_EMBED  1024
#define N_TOKENS 262144
#define FQCAP    32768

typedef __attribute__((ext_vector_type(8)))  short bf16x8;
typedef __attribute__((ext_vector_type(16))) float f32x16;

// ---------------------------------------------------------------------------
// Reference semantics (verified absmax 0.0 rounds 2-6): f32 numpy mirror
//   b_j: single fmaf chain ascending k;  a: AVX512 pairwise;  c_j: sequential
//   dist = fl(fl(a - 2b) + c); argmin first-min-wins.
// Round 8 = round 7 with the sign bug fixed: eTc stores -2e, so the MFMA
// accumulator is ALREADY -2b~; screened value is v = acc + c (round 7
// wrongly applied fmaf(-2,acc,c) on top => v = c + 4b~, argmin garbage).
// ---------------------------------------------------------------------------

__device__ __forceinline__ short f2bf_bits(float f) {
    __hip_bfloat16 h = __float2bfloat16(f);
    return *reinterpret_cast<short*>(&h);
}
__device__ __forceinline__ float bfbits2f(short s) {
    unsigned int u = ((unsigned int)(unsigned short)s) << 16;
    return __uint_as_float(u);
}

// exact replica of one dist entry: d = fl(fl(a-2b)+c), b = fmaf chain asc k
__device__ __forceinline__ float exact_d(const float* __restrict__ xrow,
                                         const float* __restrict__ emb,
                                         const float* __restrict__ csum,
                                         float a, int j) {
#pragma clang fp contract(off)
    float b = 0.f;
#pragma unroll
    for (int k = 0; k < E_DIM; ++k) b = fmaf(xrow[k], emb[k * N_EMBED + j], b);
    return (a - 2.0f * b) + csum[j];
}

// a = np.sum(x*x, axis=1) replica (AVX512 pairwise), x in registers
__device__ __forceinline__ float a_np_of(const float* x) {
#pragma clang fp contract(off)
    float s[16];
#pragma unroll
    for (int i = 0; i < 16; ++i)
        s[i] = (x[i] * x[i] + x[i + 16] * x[i + 16]) +
               (x[i + 32] * x[i + 32] + x[i + 48] * x[i + 48]);
    float hh[8];
#pragma unroll
    for (int i = 0; i < 8; ++i) hh[i] = s[i] + s[i + 8];
    float uu[4];
#pragma unroll
    for (int i = 0; i < 4; ++i) uu[i] = hh[i] + hh[i + 4];
    return (uu[0] + uu[2]) + (uu[1] + uu[3]);
}

__device__ __forceinline__ bool lexless(float av, int ai, float bv, int bi) {
    return (av < bv) || (av == bv && ai < bi);
}

// merged prep: blocks 0-255 split -2e into linear chunk layout + embed copy;
// blocks 256-259 compute c_j = sequential sum of e^2 (reference replica).
__global__ __launch_bounds__(256) void vq_prep(const float* __restrict__ emb,
                                               short* __restrict__ eTc,
                                               float* __restrict__ out_e,
                                               float* __restrict__ c_out) {
    const int b = blockIdx.x;
    if (b < 256) {
        const int t = b * 256 + threadIdx.x;   // t = k*1024 + n
        const int k = t >> 10, n = t & 1023;
        float e = emb[t];
        float m2 = -2.0f * e;
        short hb = f2bf_bits(m2);
        short lb = f2bf_bits(m2 - bfbits2f(hb));
        const int chunk = n >> 7, code = n & 127, slot = k >> 3, jj = k & 7;
        const int base = chunk * 16384 + (slot * 128 + code) * 8 + jj;
        eTc[base]        = hb;
        eTc[base + 8192] = lb;
        out_e[t] = e;
    } else {
#pragma clang fp contract(off)
        const int j = (b - 256) * 256 + threadIdx.x;
        float e = emb[j];
        float s = e * e;
        for (int k = 1; k < E_DIM; ++k) {
            float ek = emb[k * N_EMBED + j];
            float pk = ek * ek;
            s = s + pk;
        }
        c_out[j] = s;
    }
}

__device__ __forceinline__ void tile_epilogue(
    const f32x16& acc, const float* __restrict__ cvp16, int codebase_global,
    int h, float& v1, float& v2, float& v3, int& i1, int& i2) {
#pragma unroll
    for (int r = 0; r < 16; ++r) {
        const int row = (r & 3) + 8 * (r >> 2) + 4 * h;
        const float d = acc[r] + cvp16[r];   // acc = -2b~ ; v = c - 2b~
        const int idx = codebase_global + row;
        if (d < v3) {
            if (d < v1)      { v3 = v2; v2 = v1; i2 = i1; v1 = d; i1 = idx; }
            else if (d < v2) { v3 = v2; v2 = d;  i2 = idx; }
            else             { v3 = d; }
        }
    }
}

__global__ __launch_bounds__(256, 4) void vq_screen_kernel(
    const float* __restrict__ in, const float* __restrict__ emb,
    const float* __restrict__ csum, const short* __restrict__ eTc,
    float* __restrict__ out_idx,
    unsigned int* __restrict__ qcnt, unsigned int* __restrict__ fullQ)
{
    __shared__ uint4 lds_e[2048];   // [0..1024) hi, [1024..2048) lo ; 32 KB

    const int t = threadIdx.x;
    const int wave = t >> 6, l = t & 63, col = l & 31, h = l >> 5;
    const int tok = blockIdx.x * 128 + wave * 32 + col;
    const float* xrow = in + (size_t)tok * E_DIM;

    // ---- B operand (this lane's k-half): x[tok][s*16 + h*8 + j]
    float xv[4][8];
#pragma unroll
    for (int s = 0; s < 4; ++s) {
        float4 u0 = *reinterpret_cast<const float4*>(xrow + s * 16 + h * 8);
        float4 u1 = *reinterpret_cast<const float4*>(xrow + s * 16 + h * 8 + 4);
        xv[s][0] = u0.x; xv[s][1] = u0.y; xv[s][2] = u0.z; xv[s][3] = u0.w;
        xv[s][4] = u1.x; xv[s][5] = u1.y; xv[s][6] = u1.z; xv[s][7] = u1.w;
    }
    bf16x8 bhi[4], blo[4];
    float sax_h = 0.f;
#pragma unroll
    for (int s = 0; s < 4; ++s) {
#pragma unroll
        for (int j = 0; j < 8; ++j) {
            float x = xv[s][j];
            sax_h += fabsf(x);
            short hb = f2bf_bits(x);
            bhi[s][j] = hb;
            blo[s][j] = f2bf_bits(x - bfbits2f(hb));
        }
    }
    const float sax = sax_h + __shfl_xor(sax_h, 32, 64);

    // ---- exact a (AVX512-pairwise replica) via cross-half exchange
    float a_np;
    {
#pragma clang fp contract(off)
        float sv[8];
#pragma unroll
        for (int j = 0; j < 8; ++j) {
            float p0 = xv[0][j] * xv[0][j];
            float p1 = xv[1][j] * xv[1][j];
            float p2 = xv[2][j] * xv[2][j];
            float p3 = xv[3][j] * xv[3][j];
            sv[j] = (p0 + p1) + (p2 + p3);
        }
        float hh[8];
#pragma unroll
        for (int j = 0; j < 8; ++j) hh[j] = sv[j] + __shfl_xor(sv[j], 32, 64);
        float u0 = hh[0] + hh[4], u1 = hh[1] + hh[5];
        float u2 = hh[2] + hh[6], u3 = hh[3] + hh[7];
        a_np = (u0 + u2) + (u1 + u3);
    }

    // ---- top-3 trackers on v = c - 2b~ (ascending code order, strict <)
    float v1 = 3.4e38f, v2 = 3.4e38f, v3 = 3.4e38f;
    int i1 = 0, i2 = 0;

    for (int cc = 0; cc < 8; ++cc) {
        __syncthreads();
        {   // linear 32 KB copy: coalesced global reads, linear b128 LDS writes
            const uint4* gsrc = reinterpret_cast<const uint4*>(eTc) + cc * 2048;
#pragma unroll
            for (int j = 0; j < 8; ++j) lds_e[j * 256 + t] = gsrc[j * 256 + t];
        }
        __syncthreads();

        const int cb = cc << 7;
#pragma unroll
        for (int tp = 0; tp < 2; ++tp) {
            const int c0 = tp * 64 + col;
            f32x16 accA, accB;
#pragma unroll
            for (int r = 0; r < 16; ++r) { accA[r] = 0.f; accB[r] = 0.f; }
#pragma unroll
            for (int s = 0; s < 4; ++s) {
                const int slot = 2 * s + h;
                bf16x8 ahA = *reinterpret_cast<const bf16x8*>(&lds_e[slot * 128 + c0]);
                bf16x8 alA = *reinterpret_cast<const bf16x8*>(&lds_e[1024 + slot * 128 + c0]);
                bf16x8 ahB = *reinterpret_cast<const bf16x8*>(&lds_e[slot * 128 + c0 + 32]);
                bf16x8 alB = *reinterpret_cast<const bf16x8*>(&lds_e[1024 + slot * 128 + c0 + 32]);
                accA = __builtin_amdgcn_mfma_f32_32x32x16_bf16(ahA, bhi[s], accA, 0, 0, 0);
                accB = __builtin_amdgcn_mfma_f32_32x32x16_bf16(ahB, bhi[s], accB, 0, 0, 0);
                accA = __builtin_amdgcn_mfma_f32_32x32x16_bf16(ahA, blo[s], accA, 0, 0, 0);
                accB = __builtin_amdgcn_mfma_f32_32x32x16_bf16(ahB, blo[s], accB, 0, 0, 0);
                accA = __builtin_amdgcn_mfma_f32_32x32x16_bf16(alA, bhi[s], accA, 0, 0, 0);
                accB = __builtin_amdgcn_mfma_f32_32x32x16_bf16(alB, bhi[s], accB, 0, 0, 0);
            }
            // c values from global csum (4 KB, L1-resident): rows 8g+4h..+3
            float cvpA[16], cvpB[16];
#pragma unroll
            for (int g = 0; g < 4; ++g) {
                const float4 ca = *reinterpret_cast<const float4*>(&csum[cb + tp * 64 + 8 * g + 4 * h]);
                const float4 cbv4 = *reinterpret_cast<const float4*>(&csum[cb + tp * 64 + 32 + 8 * g + 4 * h]);
                cvpA[g*4+0] = ca.x;   cvpA[g*4+1] = ca.y;   cvpA[g*4+2] = ca.z;   cvpA[g*4+3] = ca.w;
                cvpB[g*4+0] = cbv4.x; cvpB[g*4+1] = cbv4.y; cvpB[g*4+2] = cbv4.z; cvpB[g*4+3] = cbv4.w;
            }
            tile_epilogue(accA, cvpA, cb + tp * 64,      h, v1, v2, v3, i1, i2);
            tile_epilogue(accB, cvpB, cb + tp * 64 + 32, h, v1, v2, v3, i1, i2);
        }
    }

    // ---- merge the two k-halves (lanes l and l^32 hold complementary rows)
    const float w1 = __shfl_xor(v1, 32, 64), w2 = __shfl_xor(v2, 32, 64), w3 = __shfl_xor(v3, 32, 64);
    const int   j1 = __shfl_xor(i1, 32, 64), j2 = __shfl_xor(i2, 32, 64);
    const bool bfirst = lexless(w1, j1, v1, i1);
    const float r1v = bfirst ? w1 : v1;  const int r1i = bfirst ? j1 : i1;
    const float cav = bfirst ? v1 : v2;  const int cai = bfirst ? i1 : i2;
    const float cbv = bfirst ? w2 : w1;  const int cbi = bfirst ? j2 : j1;
    const bool bsec = lexless(cbv, cbi, cav, cai);
    const float r2v = bsec ? cbv : cav;  const int r2i = bsec ? cbi : cai;
    const float r3v = bsec ? fminf(cav, bfirst ? w3 : w2)
                           : fminf(cbv, bfirst ? v2 : v3);

    if (l < 32) {
        // thr covers screen err (~5e-6) + reference fl(a-2b), fl(+c) double
        // rounding (<= 2*(ulp(a-2b)+ulp(d)) <= 6.2e-5 for a<150), 1.3x margin.
        const float thr = 8e-5f + 4e-7f * sax;
        const bool sane = (a_np < 150.f) && (sax < 128.f) && (fabsf(r1v) < 0.5f);
        int fin = r1i;
        if (sane && (r2v - r1v > thr)) {
            // certified: screen winner = reference argmin
        } else if (sane && (r3v - r1v > thr)) {
            // true argmin is one of {r1i, r2i}: exact pair resolve (lex tie)
            const float d1 = exact_d(xrow, emb, csum, a_np, r1i);
            const float d2 = exact_d(xrow, emb, csum, a_np, r2i);
            if (d2 < d1 || (d2 == d1 && r2i < r1i)) fin = r2i;
        } else {
            const unsigned int qi = atomicAdd(qcnt, 1u);
            if (qi < FQCAP) fullQ[qi] = (unsigned int)tok;
            // provisional fin = r1i; fallback overwrites
        }
        out_idx[tok] = (float)fin;
    }
}

// exact full rescan (reference replica) for 3-way ties / guard trips
__global__ __launch_bounds__(256) void vq_full_kernel(
    const float* __restrict__ in, const float* __restrict__ emb,
    const float* __restrict__ csum, const unsigned int* __restrict__ qcnt,
    const unsigned int* __restrict__ fullQ, float* __restrict__ out_idx) {
#pragma clang fp contract(off)
    unsigned int nq = *qcnt;
    if (nq > FQCAP) nq = FQCAP;
    const int l = threadIdx.x & 63;
    for (unsigned int w = blockIdx.x * 4 + (threadIdx.x >> 6); w < nq; w += 1024) {
        const int tok = (int)fullQ[w];
        const float* xrow = in + (size_t)tok * E_DIM;
        float x[E_DIM];
#pragma unroll
        for (int j4 = 0; j4 < 16; ++j4) {
            const float4 u = *reinterpret_cast<const float4*>(xrow + j4 * 4);
            x[j4 * 4 + 0] = u.x; x[j4 * 4 + 1] = u.y;
            x[j4 * 4 + 2] = u.z; x[j4 * 4 + 3] = u.w;
        }
        const float a = a_np_of(x);
        const int c0 = l * 16;
        float b[16];
#pragma unroll
        for (int q = 0; q < 16; ++q) b[q] = 0.f;
        for (int k = 0; k < E_DIM; ++k) {
            const float xk = x[k];
            const float* er = emb + k * N_EMBED + c0;
#pragma unroll
            for (int q = 0; q < 16; ++q) b[q] = fmaf(xk, er[q], b[q]);
        }
        float bd = 3.4e38f; int bi = 1 << 30;
#pragma unroll
        for (int q = 0; q < 16; ++q) {
            const float d = (a - 2.0f * b[q]) + csum[c0 + q];
            if (d < bd) { bd = d; bi = c0 + q; }
        }
        for (int m = 1; m < 64; m <<= 1) {
            const float od = __shfl_xor(bd, m, 64);
            const int oi = __shfl_xor(bi, m, 64);
            if (od < bd || (od == bd && oi < bi)) { bd = od; bi = oi; }
        }
        if (l == 0) out_idx[tok] = (float)bi;
    }
}

// quantize / input copy / straight-through grad (outputs 0..2), coalesced.
__global__ __launch_bounds__(256) void vq_gather_kernel(
    const float* __restrict__ in, const float* __restrict__ emb,
    const float* __restrict__ idxf,
    float* __restrict__ out_q, float* __restrict__ out_in, float* __restrict__ out_g) {
#pragma clang fp contract(off)
    const size_t j = (size_t)blockIdx.x * 256 + threadIdx.x;  // float4 index
    const int m  = (int)(j >> 4);
    const int k0 = ((int)j & 15) * 4;
    const int idx = (int)idxf[m];

    const float4 x = reinterpret_cast<const float4*>(in)[j];
    const float q0 = emb[(size_t)(k0 + 0) * N_EMBED + idx];
    const float q1 = emb[(size_t)(k0 + 1) * N_EMBED + idx];
    const float q2 = emb[(size_t)(k0 + 2) * N_EMBED + idx];
    const float q3 = emb[(size_t)(k0 + 3) * N_EMBED + idx];

    float4 q = make_float4(q0, q1, q2, q3);
    float4 g;
    g.x = x.x + (q0 - x.x);
    g.y = x.y + (q1 - x.y);
    g.z = x.z + (q2 - x.z);
    g.w = x.w + (q3 - x.w);

    reinterpret_cast<float4*>(out_q)[j]  = q;
    reinterpret_cast<float4*>(out_in)[j] = x;
    reinterpret_cast<float4*>(out_g)[j]  = g;
}

extern "C" void kernel_launch(void* const* d_in, const int* in_sizes, int n_in,
                              void* d_out, int out_size, void* d_ws, size_t ws_size,
                              hipStream_t stream) {
    const float* in  = (const float*)d_in[0];   // [262144, 64] f32
    const float* emb = (const float*)d_in[1];   // [64, 1024]  f32

    float* out     = (float*)d_out;
    float* out_q   = out;
    float* out_in  = out + (size_t)N_TOKENS * E_DIM;
    float* out_g   = out + 2ull * N_TOKENS * E_DIM;
    float* out_idx = out + 3ull * N_TOKENS * E_DIM;
    float* out_e   = out_idx + N_TOKENS;

    unsigned char* ws = (unsigned char*)d_ws;
    float*          c_ws  = (float*)(ws);                         // 4 KB
    short*          eTc   = (short*)(ws + 4096);                  // 256 KB
    unsigned int*   qcnt  = (unsigned int*)(ws + 4096 + 262144);  // 256 B pad
    unsigned int*   fullQ = (unsigned int*)(ws + 4096 + 262144 + 256); // 128 KB

    hipMemsetAsync(qcnt, 0, sizeof(unsigned int), stream);

    vq_prep<<<260, 256, 0, stream>>>(emb, eTc, out_e, c_ws);

    vq_screen_kernel<<<N_TOKENS / 128, 256, 0, stream>>>(
        in, emb, c_ws, eTc, out_idx, qcnt, fullQ);

    vq_full_kernel<<<256, 256, 0, stream>>>(in, emb, c_ws, qcnt, fullQ, out_idx);

    const int gather_blocks = (N_TOKENS * E_DIM / 4) / 256;       // 16384
    vq_gather_kernel<<<gather_blocks, 256, 0, stream>>>(in, emb, out_idx,
                                                        out_q, out_in, out_g);
}